// Round 2
// baseline (424.693 us; speedup 1.0000x reference)
//
#include <hip/hip_runtime.h>
#include <hip/hip_bf16.h>

#define L_LAYERS 4
#define B_DIM 256
#define H_DIM 65536
#define KC 2048      // K-chunk per block -> 32 splits
#define BK 32        // K per MFMA step
#define LDA 56       // padded bf16 stride for a 32-wide k tile (112 B, 16B-aligned, low-conflict)

using bf16x8_t = __attribute__((ext_vector_type(8))) short;   // 8 bf16 (4 VGPRs) MFMA operand
using shortx4  = __attribute__((ext_vector_type(4))) short;   // 8-byte LDS store
using floatx4  = __attribute__((ext_vector_type(4))) float;   // MFMA accumulator

__device__ __forceinline__ unsigned short f2bf(float f) {
    // round-to-nearest-even fp32 -> bf16 (inputs are finite normals; no NaN path needed)
    unsigned u = __float_as_uint(f);
    return (unsigned short)((u + 0x7fffu + ((u >> 16) & 1u)) >> 16);
}

__global__ __launch_bounds__(256) void gram_kernel(const float* __restrict__ hs,
                                                   float* __restrict__ G) {
    __shared__ short ldsA[128 * LDA];
    __shared__ short ldsB[128 * LDA];

    const int tid  = threadIdx.x;
    const int ta   = blockIdx.x >> 1;   // tile row-block (0/1)
    const int tb   = blockIdx.x & 1;    // tile col-block (0/1)
    const int kz   = blockIdx.y;        // K-split index (0..31)
    const int l    = blockIdx.z;        // layer

    const int wave = tid >> 6, lane = tid & 63;
    const int m0   = (wave >> 1) * 64;  // wave's row offset in 128-tile
    const int n0   = (wave & 1) * 64;   // wave's col offset
    const int mrow = lane & 15, quad = lane >> 4;

    const int tr = tid >> 3;            // staging row lane-group (0..31)
    const int tc = (tid & 7) * 4;       // staging col (float units, 0..28)

    const float* baseA = hs + ((size_t)l * B_DIM + ta * 128) * H_DIM + (size_t)kz * KC;
    const float* baseB = hs + ((size_t)l * B_DIM + tb * 128) * H_DIM + (size_t)kz * KC;

    floatx4 acc[4][4];
#pragma unroll
    for (int i = 0; i < 4; ++i)
#pragma unroll
        for (int j = 0; j < 4; ++j) acc[i][j] = (floatx4)0.0f;

    for (int kt = 0; kt < KC / BK; ++kt) {
        const int kb = kt * BK;
#pragma unroll
        for (int it = 0; it < 4; ++it) {
            const int row = it * 32 + tr;
            const float4 va = *(const float4*)(baseA + (size_t)row * H_DIM + kb + tc);
            const float4 vb = *(const float4*)(baseB + (size_t)row * H_DIM + kb + tc);
            shortx4 wa, wb;
            wa[0] = (short)f2bf(va.x); wa[1] = (short)f2bf(va.y);
            wa[2] = (short)f2bf(va.z); wa[3] = (short)f2bf(va.w);
            wb[0] = (short)f2bf(vb.x); wb[1] = (short)f2bf(vb.y);
            wb[2] = (short)f2bf(vb.z); wb[3] = (short)f2bf(vb.w);
            *(shortx4*)&ldsA[row * LDA + tc] = wa;
            *(shortx4*)&ldsB[row * LDA + tc] = wb;
        }
        __syncthreads();

        bf16x8_t af[4], bfv[4];
#pragma unroll
        for (int i = 0; i < 4; ++i)
            af[i] = *(const bf16x8_t*)&ldsA[(m0 + i * 16 + mrow) * LDA + quad * 8];
#pragma unroll
        for (int j = 0; j < 4; ++j)
            bfv[j] = *(const bf16x8_t*)&ldsB[(n0 + j * 16 + mrow) * LDA + quad * 8];
#pragma unroll
        for (int i = 0; i < 4; ++i)
#pragma unroll
            for (int j = 0; j < 4; ++j)
                acc[i][j] = __builtin_amdgcn_mfma_f32_16x16x32_bf16(af[i], bfv[j], acc[i][j], 0, 0, 0);
        __syncthreads();
    }

    // C/D layout (m89/m91 verified): col = lane&15, row = quad*4 + reg
    float* Gl = G + (size_t)l * B_DIM * B_DIM;
#pragma unroll
    for (int i = 0; i < 4; ++i)
#pragma unroll
        for (int j = 0; j < 4; ++j)
#pragma unroll
            for (int r = 0; r < 4; ++r) {
                const int row = ta * 128 + m0 + i * 16 + quad * 4 + r;
                const int col = tb * 128 + n0 + j * 16 + mrow;
                atomicAdd(&Gl[row * B_DIM + col], acc[i][j][r]);
            }
}

__global__ __launch_bounds__(256) void loss_kernel(const float* __restrict__ G,
                                                   const int* __restrict__ task,
                                                   float* __restrict__ out) {
    const int i = blockIdx.x, l = blockIdx.y, j = threadIdx.x;

    // Detect task_type width (int64 vs int32) BLOCK-UNIFORMLY.
    // If int64 little-endian with values 0..15, all odd 32-bit words are 0.
    // If int32 (values 0..15 random), some odd-index word is nonzero w.p. ~1.
    // Only the first 256 words are probed (in-bounds under either layout).
    __shared__ int s_odd_nz;
    if (j == 0) s_odd_nz = 0;
    __syncthreads();
    if (j < 128 && task[2 * j + 1] != 0) s_odd_nz = 1;   // benign race: all write 1
    __syncthreads();
    const bool is64 = (s_odd_nz == 0);

    const float* Gl = G + (size_t)l * B_DIM * B_DIM;
    const float gij = Gl[i * B_DIM + j];
    const float gii = Gl[i * B_DIM + i];
    const float gjj = Gl[j * B_DIM + j];
    const float nd  = gij * rsqrtf(gii) * rsqrtf(gjj);
    const float d2  = fmaxf(2.0f - 2.0f * nd, 0.0f);
    const float w   = __expf(-2.0f * d2);   // exp(-d2 / 0.5)

    const int ti = is64 ? task[2 * i] : task[i];
    const int tj = is64 ? task[2 * j] : task[j];
    const float pm = (ti == tj && i != j) ? 1.0f : 0.0f;

    float a = w * pm, b = w;
#pragma unroll
    for (int off = 32; off > 0; off >>= 1) {
        a += __shfl_down(a, off);
        b += __shfl_down(b, off);
    }
    __shared__ float sa[4], sb[4];
    const int wv = j >> 6, ln = j & 63;
    if (ln == 0) { sa[wv] = a; sb[wv] = b; }
    __syncthreads();
    if (j == 0) {
        const float A  = sa[0] + sa[1] + sa[2] + sa[3];
        const float Bb = sb[0] + sb[1] + sb[2] + sb[3];
        const float c  = -logf((A + 1e-8f) / (Bb + 1e-8f)) * (0.2f / 1024.0f);
        atomicAdd(out, c);
    }
}

extern "C" void kernel_launch(void* const* d_in, const int* in_sizes, int n_in,
                              void* d_out, int out_size, void* d_ws, size_t ws_size,
                              hipStream_t stream) {
    const float* hs   = (const float*)d_in[0];
    const int*   task = (const int*)d_in[1];
    float*       out  = (float*)d_out;
    float*       G    = (float*)d_ws;   // L*B*B fp32 = 1 MiB

    hipMemsetAsync(G, 0, (size_t)L_LAYERS * B_DIM * B_DIM * sizeof(float), stream);
    hipMemsetAsync(out, 0, sizeof(float), stream);

    dim3 grid(4, H_DIM / KC, L_LAYERS);   // tiles fastest-varying for L3 reuse
    gram_kernel<<<grid, dim3(256), 0, stream>>>(hs, G);
    loss_kernel<<<dim3(B_DIM, L_LAYERS), dim3(256), 0, stream>>>(G, task, out);
}

// Round 3
// 423.181 us; speedup vs baseline: 1.0036x; 1.0036x over previous
//
#include <hip/hip_runtime.h>
#include <hip/hip_bf16.h>

#define L_LAYERS 4
#define B_DIM 256
#define H_DIM 65536
#define KC 1024                    // K-chunk per block -> 64 splits per layer
#define BK 32                      // K per MFMA step
#define NKZ (H_DIM / KC)           // 64
#define NSLICE (L_LAYERS * NKZ)    // 256 partial-Gram slices
#define LDSTR 40                   // shorts per LDS row (80 B: 16B-aligned, max 2-way bank conflict)

using bf16x8_t = __attribute__((ext_vector_type(8))) short;   // MFMA A/B operand (4 VGPRs)
using shortx8  = __attribute__((ext_vector_type(8))) short;   // 16-byte LDS store
using floatx4  = __attribute__((ext_vector_type(4))) float;   // MFMA accumulator

__device__ __forceinline__ unsigned short f2bf(float f) {
    // round-to-nearest-even fp32 -> bf16 (finite inputs)
    unsigned u = __float_as_uint(f);
    return (unsigned short)((u + 0x7fffu + ((u >> 16) & 1u)) >> 16);
}

// One block per (layer, kz): reads 256 rows x KC floats EXACTLY ONCE (1x fetch),
// computes the full 256x256 Gram partial, stores it to its own slice (no atomics).
__global__ __launch_bounds__(512, 2) void gram_kernel(const float* __restrict__ hs,
                                                      float* __restrict__ S) {
    __shared__ short lds[B_DIM * LDSTR];   // 256 x 40 shorts = 20 KB

    const int tid = threadIdx.x;
    const int bx  = blockIdx.x;            // 0..255
    const int l   = bx >> 6;
    const int kz  = bx & (NKZ - 1);

    const int wave = tid >> 6, lane = tid & 63;
    const int wm = wave >> 1;              // 0..3: 64-row strip
    const int wn = wave & 1;               // 0..1: 128-col strip
    const int mrow = lane & 15, quad = lane >> 4;

    // staging: thread t covers row r = t>>1, floats [h*16, h*16+16)
    const int r = tid >> 1;
    const int h = tid & 1;
    const float* gp = hs + ((size_t)l * B_DIM + r) * H_DIM + (size_t)kz * KC + h * 16;
    const int ldsw = r * LDSTR + h * 16;   // short units

    floatx4 acc[4][8];
#pragma unroll
    for (int i = 0; i < 4; ++i)
#pragma unroll
        for (int j = 0; j < 8; ++j) acc[i][j] = (floatx4)0.0f;

    // register prefetch of K-slice 0
    float4 pv0 = *(const float4*)(gp + 0);
    float4 pv1 = *(const float4*)(gp + 4);
    float4 pv2 = *(const float4*)(gp + 8);
    float4 pv3 = *(const float4*)(gp + 12);

    for (int kt = 0; kt < KC / BK; ++kt) {
        // convert current slice to bf16 and stage to LDS
        shortx8 w0, w1;
        w0[0] = (short)f2bf(pv0.x); w0[1] = (short)f2bf(pv0.y);
        w0[2] = (short)f2bf(pv0.z); w0[3] = (short)f2bf(pv0.w);
        w0[4] = (short)f2bf(pv1.x); w0[5] = (short)f2bf(pv1.y);
        w0[6] = (short)f2bf(pv1.z); w0[7] = (short)f2bf(pv1.w);
        w1[0] = (short)f2bf(pv2.x); w1[1] = (short)f2bf(pv2.y);
        w1[2] = (short)f2bf(pv2.z); w1[3] = (short)f2bf(pv2.w);
        w1[4] = (short)f2bf(pv3.x); w1[5] = (short)f2bf(pv3.y);
        w1[6] = (short)f2bf(pv3.z); w1[7] = (short)f2bf(pv3.w);
        *(shortx8*)&lds[ldsw]     = w0;    // previous iteration's trailing barrier protects this
        *(shortx8*)&lds[ldsw + 8] = w1;

        // issue next slice's loads; they land during the MFMA phase
        if (kt < KC / BK - 1) {
            const float* gn = gp + (kt + 1) * BK;
            pv0 = *(const float4*)(gn + 0);
            pv1 = *(const float4*)(gn + 4);
            pv2 = *(const float4*)(gn + 8);
            pv3 = *(const float4*)(gn + 12);
        }
        __syncthreads();

        bf16x8_t af[4], bfv[8];
#pragma unroll
        for (int i = 0; i < 4; ++i)
            af[i] = *(const bf16x8_t*)&lds[(wm * 64 + i * 16 + mrow) * LDSTR + quad * 8];
#pragma unroll
        for (int j = 0; j < 8; ++j)
            bfv[j] = *(const bf16x8_t*)&lds[(wn * 128 + j * 16 + mrow) * LDSTR + quad * 8];
#pragma unroll
        for (int i = 0; i < 4; ++i)
#pragma unroll
            for (int j = 0; j < 8; ++j)
                acc[i][j] = __builtin_amdgcn_mfma_f32_16x16x32_bf16(af[i], bfv[j], acc[i][j], 0, 0, 0);
        __syncthreads();
    }

    // store this block's partial Gram to its own slice (plain coalesced-ish stores)
    float* Ssl = S + (size_t)bx * (B_DIM * B_DIM);
#pragma unroll
    for (int i = 0; i < 4; ++i)
#pragma unroll
        for (int j = 0; j < 8; ++j)
#pragma unroll
            for (int rr = 0; rr < 4; ++rr) {
                const int row = wm * 64 + i * 16 + quad * 4 + rr;
                const int col = wn * 128 + j * 16 + mrow;
                Ssl[row * B_DIM + col] = acc[i][j][rr];
            }
}

// G[l,i,j] = sum over kz of S[(l*NKZ+kz), i, j] — pure streaming reduce
__global__ __launch_bounds__(256) void reduce_kernel(const float* __restrict__ S,
                                                     float* __restrict__ G) {
    const int li = blockIdx.x;             // l*256 + i
    const int j  = threadIdx.x;
    const int l  = li >> 8;
    const int i  = li & 255;
    const float* base = S + ((size_t)l * NKZ) * (B_DIM * B_DIM) + i * B_DIM + j;
    float s = 0.0f;
#pragma unroll
    for (int kz = 0; kz < NKZ; ++kz)
        s += base[(size_t)kz * (B_DIM * B_DIM)];
    G[(size_t)li * B_DIM + j] = s;         // == G[l*65536 + i*256 + j]
}

__global__ __launch_bounds__(256) void loss_kernel(const float* __restrict__ G,
                                                   const int* __restrict__ task,
                                                   float* __restrict__ out) {
    const int i = blockIdx.x, l = blockIdx.y, j = threadIdx.x;

    // block-uniform int64-vs-int32 detection for task_type (proven in R2)
    __shared__ int s_odd_nz;
    if (j == 0) s_odd_nz = 0;
    __syncthreads();
    if (j < 128 && task[2 * j + 1] != 0) s_odd_nz = 1;
    __syncthreads();
    const bool is64 = (s_odd_nz == 0);

    const float* Gl = G + (size_t)l * B_DIM * B_DIM;
    const float gij = Gl[i * B_DIM + j];
    const float gii = Gl[i * B_DIM + i];
    const float gjj = Gl[j * B_DIM + j];
    const float nd  = gij * rsqrtf(gii) * rsqrtf(gjj);
    const float d2  = fmaxf(2.0f - 2.0f * nd, 0.0f);
    const float w   = __expf(-2.0f * d2);   // exp(-d2 / 0.5)

    const int ti = is64 ? task[2 * i] : task[i];
    const int tj = is64 ? task[2 * j] : task[j];
    const float pm = (ti == tj && i != j) ? 1.0f : 0.0f;

    float a = w * pm, b = w;
#pragma unroll
    for (int off = 32; off > 0; off >>= 1) {
        a += __shfl_down(a, off);
        b += __shfl_down(b, off);
    }
    __shared__ float sa[4], sb[4];
    const int wv = j >> 6, ln = j & 63;
    if (ln == 0) { sa[wv] = a; sb[wv] = b; }
    __syncthreads();
    if (j == 0) {
        const float A  = sa[0] + sa[1] + sa[2] + sa[3];
        const float Bb = sb[0] + sb[1] + sb[2] + sb[3];
        const float c  = -logf((A + 1e-8f) / (Bb + 1e-8f)) * (0.2f / 1024.0f);
        atomicAdd(out, c);
    }
}

extern "C" void kernel_launch(void* const* d_in, const int* in_sizes, int n_in,
                              void* d_out, int out_size, void* d_ws, size_t ws_size,
                              hipStream_t stream) {
    const float* hs   = (const float*)d_in[0];
    const int*   task = (const int*)d_in[1];
    float*       out  = (float*)d_out;

    float* S = (float*)d_ws;                              // 256 slices x 256 KB = 64 MB
    float* G = S + (size_t)NSLICE * (B_DIM * B_DIM);      // +1 MB

    hipMemsetAsync(out, 0, sizeof(float), stream);

    gram_kernel<<<dim3(NSLICE), dim3(512), 0, stream>>>(hs, S);
    reduce_kernel<<<dim3(L_LAYERS * B_DIM), dim3(256), 0, stream>>>(S, G);
    loss_kernel<<<dim3(B_DIM, L_LAYERS), dim3(256), 0, stream>>>(G, task, out);
}